// Round 16
// baseline (369.985 us; speedup 1.0000x reference)
//
#include <hip/hip_runtime.h>

typedef unsigned short u16;
typedef short s16x8 __attribute__((ext_vector_type(8)));
typedef float f32x4 __attribute__((ext_vector_type(4)));
typedef u16 u16x4 __attribute__((ext_vector_type(4)));

#define NN 50000
#define NE 300000
#define HH 256
#define NCHUNK 196
#define NRC 98           // ceil(50000/512) row-chunks of 512 (2 tiles x 256)
#define NPB 12500        // xprep2 blocks (50000/4)

__device__ __forceinline__ float b2f(u16 u) {
  union { float f; unsigned int i; } v; v.i = ((unsigned int)u) << 16; return v.f;
}
__device__ __forceinline__ u16 f2b(float f) {
  union { float f; unsigned int i; } v; v.f = f;
  unsigned int u = v.i;
  unsigned int r = (u + 0x7fffu + ((u >> 16) & 1u)) >> 16;
  return (u16)r;
}
__device__ __forceinline__ float lrelu(float x) { return x > 0.f ? x : 0.2f * x; }

#define GLOAD_LDS16(SRC, DST)                                                   \
  __builtin_amdgcn_global_load_lds(                                             \
      (const __attribute__((address_space(1))) void*)(SRC),                     \
      (__attribute__((address_space(3))) void*)(DST), 16, 0, 0)

__device__ __forceinline__ f32x4 MFMA(s16x8 a, s16x8 b, f32x4 c) {
  return __builtin_amdgcn_mfma_f32_16x16x32_bf16(a, b, c, 0, 0, 0);
}

// ---------------------------------------------------------------------------
// Stage one 128-col half of B^T (64KB) into LDS (layout: q*16384 + nf*2048 +
// ks*1024 + cq*256 + colL*16; source-permuted, linear dest — r13-verified).
// COL MAP (r15): fragment slot (nf,colL) computes logical col = half*128 +
// colL*8 + nf. 8-wave version: 64 chunks = 8 rounds x 8 waves.
__device__ __forceinline__ void stageBhalf(const u16* __restrict__ BT, int half,
                                           char* lds, int lane, int wid) {
#pragma unroll
  for (int j = 0; j < 8; ++j) {
    int idx = j * 8 + wid;               // 0..63 x 1KB chunks
    int q = idx >> 4, rem = idx & 15;
    int nf = rem >> 1, ks = rem & 1;
    int col = half * 128 + (lane & 15) * 8 + nf;   // r15 col map
    GLOAD_LDS16((const char*)BT + col * 512 + q * 128 + ks * 64 + (lane >> 4) * 16,
                lds + idx * 1024);
  }
}

// Per row-tile compute: 32 rows/wave x 128 cols, K=256, B LDS-resident.
#define SGEMM_TILE(APTR, ASTRIDE, ACOLOFF)                                      \
  f32x4 acc[2][8] = {};                                                         \
  {                                                                             \
    s16x8 a[2][8];                                                              \
    const u16* a0p = (APTR) + (size_t)ar0 * (ASTRIDE) + (ACOLOFF) + cq8;        \
    const u16* a1p = (APTR) + (size_t)ar1 * (ASTRIDE) + (ACOLOFF) + cq8;        \
    _Pragma("unroll")                                                           \
    for (int ksp = 0; ksp < 8; ++ksp) {                                         \
      a[0][ksp] = *(const s16x8*)(a0p + ksp * 32);                              \
      a[1][ksp] = *(const s16x8*)(a1p + ksp * 32);                              \
    }                                                                           \
    _Pragma("unroll")                                                           \
    for (int ksp = 0; ksp < 8; ++ksp) {                                         \
      const char* bb = lds + (ksp >> 1) * 16384 + (ksp & 1) * 1024 + lane * 16; \
      _Pragma("unroll")                                                         \
      for (int nf = 0; nf < 8; ++nf) {                                          \
        s16x8 bf = *(const s16x8*)(bb + nf * 2048);                             \
        acc[0][nf] = MFMA(a[0][ksp], bf, acc[0][nf]);                           \
        acc[1][nf] = MFMA(a[1][ksp], bf, acc[1][nf]);                           \
      }                                                                         \
    }                                                                           \
  }

// ---------------------------------------------------------------------------
// hgemm_s: h = xb @ Wg[b] (no bias). Writes h768 raw + partial s/d dots.
// 512 threads (8 waves), 2 row-tiles of 256.
__global__ __launch_bounds__(512) void hgemm_s(
    const u16* __restrict__ xb, const u16* __restrict__ WT,
    const float* __restrict__ asrc, const float* __restrict__ adst,
    u16* __restrict__ h768, float* __restrict__ pSd, float* __restrict__ pDd,
    int M) {
  __shared__ __align__(16) char lds[65536];
  int cid = blockIdx.x;                      // 6 * NRC
  int rem = cid % 6, chunk = cid / 6;
  int b = rem >> 1, half = rem & 1;
  int tid = threadIdx.x, lane = tid & 63, wid = tid >> 6;
  int colL = lane & 15, cq = lane >> 4, cq8 = cq * 8;

  stageBhalf(WT + (size_t)b * 65536, half, lds, lane, wid);

  float a4[8], dd4[8];
#pragma unroll
  for (int nf = 0; nf < 8; ++nf) {
    int c = half * 128 + colL * 8 + nf;          // r15 col map
    a4[nf] = asrc[b * 256 + c];
    dd4[nf] = adst[b * 256 + c];
  }
  float* st1 = pSd + (size_t)(b * 2 + half) * NN;
  float* st2 = pDd + (size_t)(b * 2 + half) * NN;
  __syncthreads();

  for (int rt = 0; rt < 2; ++rt) {
    int rowbase = chunk * 512 + rt * 256 + wid * 32;
    if (rowbase >= M) break;
    int ar0 = rowbase + colL; if (ar0 > M - 1) ar0 = M - 1;
    int ar1 = ar0 + 16; if (ar1 > M - 1) ar1 = M - 1;
    SGEMM_TILE(xb, 256, 0)
#pragma unroll
    for (int i = 0; i < 2; ++i)
#pragma unroll
      for (int r = 0; r < 4; ++r) {
        float sp = 0.f, dp = 0.f;
#pragma unroll
        for (int nf = 0; nf < 8; ++nf) {
          float v = acc[i][nf][r];
          sp += v * a4[nf]; dp += v * dd4[nf];
        }
#pragma unroll
        for (int m = 1; m < 16; m <<= 1) { sp += __shfl_xor(sp, m); dp += __shfl_xor(dp, m); }
        int row = rowbase + i * 16 + cq * 4 + r;
        if (row < M) {
          if (colL == 0) { st1[row] = sp; st2[row] = dp; }
          s16x8 o;
#pragma unroll
          for (int nf = 0; nf < 8; ++nf) o[nf] = (short)f2b(acc[i][nf][r]);
          *(s16x8*)(h768 + (size_t)row * 768 + b * 256 + half * 128 + colL * 8) = o;
        }
      }
  }
}

// ---------------------------------------------------------------------------
// wsgemm_s: y_raw[b] = A_b @ Ws[b] + bias (raw, pre-LN). Partial sum/sumsq.
__global__ __launch_bounds__(512) void wsgemm_s(
    const u16* __restrict__ xiall, const u16* __restrict__ xb,
    const u16* __restrict__ WT, const float* __restrict__ bs,
    u16* __restrict__ y_raw, float* __restrict__ pS, float* __restrict__ pQ,
    int M) {
  __shared__ __align__(16) char lds[65536];
  int cid = blockIdx.x;                      // 8 * NRC
  int rem = cid & 7, chunk = cid >> 3;
  int b = rem >> 1, half = rem & 1;
  int tid = threadIdx.x, lane = tid & 63, wid = tid >> 6;
  int colL = lane & 15, cq = lane >> 4, cq8 = cq * 8;

  const u16* Ap = (b < 3) ? xiall : xb;
  int strideA = (b < 3) ? 768 : 256;
  int coloffA = (b < 3) ? b * 256 : 0;

  stageBhalf(WT + (size_t)(3 + b) * 65536, half, lds, lane, wid);

  float bv[8];
#pragma unroll
  for (int nf = 0; nf < 8; ++nf)
    bv[nf] = bs[b * 256 + half * 128 + colL * 8 + nf];   // r15 col map
  float* st1 = pS + (size_t)(b * 2 + half) * NN;
  float* st2 = pQ + (size_t)(b * 2 + half) * NN;
  u16* yb = y_raw + (size_t)b * NN * 256;
  __syncthreads();

  for (int rt = 0; rt < 2; ++rt) {
    int rowbase = chunk * 512 + rt * 256 + wid * 32;
    if (rowbase >= M) break;
    int ar0 = rowbase + colL; if (ar0 > M - 1) ar0 = M - 1;
    int ar1 = ar0 + 16; if (ar1 > M - 1) ar1 = M - 1;
    SGEMM_TILE(Ap, strideA, coloffA)
#pragma unroll
    for (int i = 0; i < 2; ++i)
#pragma unroll
      for (int r = 0; r < 4; ++r) {
        float s = 0.f, q = 0.f;
#pragma unroll
        for (int nf = 0; nf < 8; ++nf) {
          float v = acc[i][nf][r] + bv[nf];
          acc[i][nf][r] = v;
          s += v; q += v * v;
        }
#pragma unroll
        for (int m = 1; m < 16; m <<= 1) { s += __shfl_xor(s, m); q += __shfl_xor(q, m); }
        int row = rowbase + i * 16 + cq * 4 + r;
        if (row < M) {
          if (colL == 0) { st1[row] = s; st2[row] = q; }
          s16x8 o;
#pragma unroll
          for (int nf = 0; nf < 8; ++nf) o[nf] = (short)f2b(acc[i][nf][r]);
          *(s16x8*)(yb + (size_t)row * 256 + half * 128 + colL * 8) = o;
        }
      }
  }
}

// ---------------------------------------------------------------------------
// fingemm_s: z_raw = comb @ Wf + bf (raw). Partial sum/sumsq.
__global__ __launch_bounds__(512) void fingemm_s(
    const u16* __restrict__ comb, const u16* __restrict__ WT7,
    const float* __restrict__ bfv, u16* __restrict__ z_raw,
    float* __restrict__ pFS, float* __restrict__ pFQ, int M) {
  __shared__ __align__(16) char lds[65536];
  int cid = blockIdx.x;                      // 2 * NRC
  int half = cid & 1, chunk = cid >> 1;
  int tid = threadIdx.x, lane = tid & 63, wid = tid >> 6;
  int colL = lane & 15, cq = lane >> 4, cq8 = cq * 8;

  stageBhalf(WT7, half, lds, lane, wid);

  float bv[8];
#pragma unroll
  for (int nf = 0; nf < 8; ++nf)
    bv[nf] = bfv[half * 128 + colL * 8 + nf];            // r15 col map
  float* st1 = pFS + (size_t)half * NN;
  float* st2 = pFQ + (size_t)half * NN;
  __syncthreads();

  for (int rt = 0; rt < 2; ++rt) {
    int rowbase = chunk * 512 + rt * 256 + wid * 32;
    if (rowbase >= M) break;
    int ar0 = rowbase + colL; if (ar0 > M - 1) ar0 = M - 1;
    int ar1 = ar0 + 16; if (ar1 > M - 1) ar1 = M - 1;
    SGEMM_TILE(comb, 256, 0)
#pragma unroll
    for (int i = 0; i < 2; ++i)
#pragma unroll
      for (int r = 0; r < 4; ++r) {
        float s = 0.f, q = 0.f;
#pragma unroll
        for (int nf = 0; nf < 8; ++nf) {
          float v = acc[i][nf][r] + bv[nf];
          acc[i][nf][r] = v;
          s += v; q += v * v;
        }
#pragma unroll
        for (int m = 1; m < 16; m <<= 1) { s += __shfl_xor(s, m); q += __shfl_xor(q, m); }
        int row = rowbase + i * 16 + cq * 4 + r;
        if (row < M) {
          if (colL == 0) { st1[row] = s; st2[row] = q; }
          s16x8 o;
#pragma unroll
          for (int nf = 0; nf < 8; ++nf) o[nf] = (short)f2b(acc[i][nf][r]);
          *(s16x8*)(z_raw + (size_t)row * 256 + half * 128 + colL * 8) = o;
        }
      }
  }
}

// ---------------------------------------------------------------------------
// sdfix: s_arr[b*NN+v] = pSd[2b][v] + pSd[2b+1][v]; same for d.
__global__ void sdfix(const float* __restrict__ pSd, const float* __restrict__ pDd,
                      float* __restrict__ s_arr, float* __restrict__ d_arr) {
  int i = blockIdx.x * 256 + threadIdx.x;
  if (i >= 3 * NN) return;
  int b = i / NN, v = i - b * NN;
  s_arr[i] = pSd[(size_t)(2 * b) * NN + v] + pSd[(size_t)(2 * b + 1) * NN + v];
  d_arr[i] = pDd[(size_t)(2 * b) * NN + v] + pDd[(size_t)(2 * b + 1) * NN + v];
}

// ln4: comb[v] = sum_b sw[b] * relu(LN_b(y_raw[b][v])); one wave per row.
__global__ void ln4(const u16* __restrict__ y_raw, const float* __restrict__ pS,
                    const float* __restrict__ pQ, const float* __restrict__ gs,
                    const float* __restrict__ betas, const float* __restrict__ sw,
                    u16* __restrict__ comb) {
  int v = blockIdx.x * 4 + (threadIdx.x >> 6);
  int lane = threadIdx.x & 63;
  int c0 = lane * 4;
  float accv[4] = {0.f, 0.f, 0.f, 0.f};
#pragma unroll
  for (int b = 0; b < 4; ++b) {
    float s = pS[(size_t)(2 * b) * NN + v] + pS[(size_t)(2 * b + 1) * NN + v];
    float q = pQ[(size_t)(2 * b) * NN + v] + pQ[(size_t)(2 * b + 1) * NN + v];
    float mu = s * (1.0f / HH);
    float var = q * (1.0f / HH) - mu * mu;
    float rs = rsqrtf(var + 1e-5f);
    float w = sw[b];
    u16x4 yv = *(const u16x4*)(y_raw + ((size_t)b * NN + v) * 256 + c0);
#pragma unroll
    for (int k = 0; k < 4; ++k) {
      float t = (b2f(yv[k]) - mu) * rs * gs[b * 256 + c0 + k] + betas[b * 256 + c0 + k];
      accv[k] += w * (t > 0.f ? t : 0.f);
    }
  }
  u16x4 o;
#pragma unroll
  for (int k = 0; k < 4; ++k) o[k] = f2b(accv[k]);
  *(u16x4*)(comb + (size_t)v * 256 + c0) = o;
}

// lnout: out[v] = relu(LN(z_raw[v])) as f32; one wave per row.
__global__ void lnout(const u16* __restrict__ z_raw, const float* __restrict__ pFS,
                      const float* __restrict__ pFQ, const float* __restrict__ gf,
                      const float* __restrict__ betaf, float* __restrict__ outf) {
  int v = blockIdx.x * 4 + (threadIdx.x >> 6);
  int lane = threadIdx.x & 63;
  int c0 = lane * 4;
  float s = pFS[v] + pFS[(size_t)NN + v];
  float q = pFQ[v] + pFQ[(size_t)NN + v];
  float mu = s * (1.0f / HH);
  float var = q * (1.0f / HH) - mu * mu;
  float rs = rsqrtf(var + 1e-5f);
  u16x4 zv = *(const u16x4*)(z_raw + (size_t)v * 256 + c0);
  f32x4 o;
#pragma unroll
  for (int k = 0; k < 4; ++k) {
    float t = (b2f(zv[k]) - mu) * rs * gf[c0 + k] + betaf[c0 + k];
    o[k] = t > 0.f ? t : 0.f;
  }
  *(f32x4*)(outf + (size_t)v * 256 + c0) = o;
}

// ---------------------------------------------------------------------------
// xprep2: one row per wave, no loop; per-block column partials (no atomics).
__global__ void xprep2(const float* __restrict__ x, u16* __restrict__ xb,
                       float* __restrict__ pg) {
  int tid = threadIdx.x, lane = tid & 63, w = tid >> 6;
  int r = blockIdx.x * 4 + w;
  f32x4 v = *(const f32x4*)(x + (size_t)r * HH + lane * 4);
  u16x4 o;
#pragma unroll
  for (int k = 0; k < 4; ++k) o[k] = f2b(v[k]);
  *(u16x4*)(xb + (size_t)r * HH + lane * 4) = o;
  __shared__ f32x4 sh[256];
  sh[tid] = v;
  __syncthreads();
  if (tid < 64) {
    f32x4 t = sh[tid] + sh[tid + 64] + sh[tid + 128] + sh[tid + 192];
    *(f32x4*)(pg + (size_t)blockIdx.x * 256 + lane * 4) = t;
  }
}

__global__ void gsum_red(const float* __restrict__ pg, float* __restrict__ g_sum) {
  int t = threadIdx.x;
  int r0 = blockIdx.x * 98;
  float s = 0.f;
  for (int r = r0; r < r0 + 98 && r < NPB; ++r) s += pg[(size_t)r * 256 + t];
  atomicAdd(&g_sum[t], s);
}

// 8 weight transposes: WT[z][n][k] = bf16(src_z[k][n])
__global__ void transpose_all(const float* __restrict__ Wg, const float* __restrict__ Wsm,
                              const float* __restrict__ Wf, u16* __restrict__ WT) {
  __shared__ float tile[32][33];
  int z = blockIdx.z;
  const float* src = (z < 3) ? (Wg + (size_t)z * 65536)
                   : (z < 7) ? (Wsm + (size_t)(z - 3) * 65536) : Wf;
  u16* dst = WT + (size_t)z * 65536;
  int tx = threadIdx.x, ty = threadIdx.y;
  int bx = blockIdx.x, by = blockIdx.y;
#pragma unroll
  for (int j = 0; j < 32; j += 8)
    tile[ty + j][tx] = src[(size_t)(by * 32 + ty + j) * 256 + bx * 32 + tx];
  __syncthreads();
#pragma unroll
  for (int j = 0; j < 32; j += 8)
    dst[(size_t)(bx * 32 + ty + j) * 256 + by * 32 + tx] = f2b(tile[tx][ty + j]);
}

__global__ void selector_kernel(const float* __restrict__ g_sum,
                                const float* __restrict__ W1, const float* __restrict__ b1,
                                const float* __restrict__ W2, const float* __restrict__ b2,
                                float* __restrict__ sw) {
  __shared__ float gg[256];
  __shared__ float hid[128];
  __shared__ float lg[4];
  int t = threadIdx.x;  // 128
  gg[t] = g_sum[t] * (1.0f / NN);
  gg[t + 128] = g_sum[t + 128] * (1.0f / NN);
  __syncthreads();
  float a = 0.f;
  for (int c = 0; c < 256; ++c) a += gg[c] * W1[c * 128 + t];
  a += b1[t];
  hid[t] = a > 0.f ? a : 0.f;
  __syncthreads();
  if (t < 4) {
    float s = 0.f;
    for (int j = 0; j < 128; ++j) s += hid[j] * W2[j * 4 + t];
    lg[t] = s + b2[t];
  }
  __syncthreads();
  if (t == 0) {
    float m = fmaxf(fmaxf(lg[0], lg[1]), fmaxf(lg[2], lg[3]));
    float e0 = __expf(lg[0] - m), e1 = __expf(lg[1] - m);
    float e2 = __expf(lg[2] - m), e3 = __expf(lg[3] - m);
    float inv = 1.0f / (e0 + e1 + e2 + e3);
    sw[0] = e0 * inv; sw[1] = e1 * inv; sw[2] = e2 * inv; sw[3] = e3 * inv;
  }
}

// ---------------------------------------------------------------------------
__global__ void detect_kernel(const int* __restrict__ ei_raw, int* __restrict__ flag) {
  int t = threadIdx.x;
  int nz = 0;
  for (int k = t; k < 1024; k += 256) nz |= (ei_raw[2 * k + 1] != 0);
  if (nz) atomicOr(flag, 1);
}

__global__ void norm_edges(const int* __restrict__ ei_raw, const int* __restrict__ ea_raw,
                           const int* __restrict__ flag, int* __restrict__ srcE,
                           int* __restrict__ dstE, int* __restrict__ attrE) {
  int e = blockIdx.x * 256 + threadIdx.x;
  if (e >= NE) return;
  if (*flag) {
    srcE[e] = ei_raw[e];
    dstE[e] = ei_raw[NE + e];
    attrE[e] = ea_raw[e];
  } else {
    srcE[e] = ei_raw[2 * e];
    dstE[e] = ei_raw[2 * NE + 2 * e];
    attrE[e] = ea_raw[2 * e];
  }
}

__global__ void hist_kernel(const int* __restrict__ dstE, const int* __restrict__ attrE,
                            int* __restrict__ counts) {
  int e = blockIdx.x * 256 + threadIdx.x;
  if (e < NE) {
    int a = attrE[e];
    if ((unsigned)a < 3u) atomicAdd(&counts[a * NN + dstE[e]], 1);
  }
}

__global__ void scan1(const int* __restrict__ counts, int* __restrict__ offs,
                      int* __restrict__ bsum) {
  int b = blockIdx.y, c = blockIdx.x, t = threadIdx.x;
  int idx = c * 256 + t;
  int v = (idx < NN) ? counts[b * NN + idx] : 0;
  __shared__ int sh[256];
  sh[t] = v;
  __syncthreads();
  for (int o = 1; o < 256; o <<= 1) {
    int add = (t >= o) ? sh[t - o] : 0;
    __syncthreads();
    sh[t] += add;
    __syncthreads();
  }
  int incl = sh[t];
  if (idx < NN) offs[b * (NN + 1) + idx] = incl - v;
  if (t == 255) bsum[b * NCHUNK + c] = incl;
}

__global__ void scan2(const int* __restrict__ bsum, int* __restrict__ bpre,
                      int* __restrict__ offs) {
  int t = threadIdx.x;
  if (t < 3) {
    int run = 0;
    for (int c = 0; c < NCHUNK; ++c) { bpre[t * NCHUNK + c] = run; run += bsum[t * NCHUNK + c]; }
    offs[t * (NN + 1) + NN] = run;
  }
}

__global__ void scan3(const int* __restrict__ bpre, int* __restrict__ offs,
                      int* __restrict__ cur) {
  int b = blockIdx.y, c = blockIdx.x;
  int idx = c * 256 + threadIdx.x;
  if (idx < NN) {
    int val = offs[b * (NN + 1) + idx] + bpre[b * NCHUNK + c];
    offs[b * (NN + 1) + idx] = val;
    cur[b * NN + idx] = val;
  }
}

__global__ void scatter_kernel(const int* __restrict__ srcE, const int* __restrict__ dstE,
                               const int* __restrict__ attrE, int* __restrict__ cur,
                               int* __restrict__ elist) {
  int e = blockIdx.x * 256 + threadIdx.x;
  if (e < NE) {
    int a = attrE[e];
    if ((unsigned)a < 3u) {
      int p = atomicAdd(&cur[a * NN + dstE[e]], 1);
      elist[a * NE + p] = srcE[e];
    }
  }
}

// ---------------------------------------------------------------------------
// GAT aggregation, 3 branches in one dispatch. Single-pass softmax (r15):
// logits lrelu(s+d) are O(1), exp() overflow-safe without max-subtraction.
__global__ void gat3(const int* __restrict__ offs, const int* __restrict__ elist,
                     const float* __restrict__ s_all, const float* __restrict__ d_all,
                     const u16* __restrict__ h, const float* __restrict__ bg,
                     u16* __restrict__ xiall) {
  int b = blockIdx.y;
  const int* offs_b = offs + (size_t)b * (NN + 1);
  const int* elist_b = elist + (size_t)b * NE;
  const float* s = s_all + (size_t)b * NN;
  const float* d = d_all + (size_t)b * NN;
  const float* bgrow = bg + b * 256;
  int v = blockIdx.x * 4 + (threadIdx.x >> 6);
  int lane = threadIdx.x & 63;
  float dv = d[v], sv = s[v];
  int beg = offs_b[v], end = offs_b[v + 1];
  float wself = __expf(lrelu(sv + dv));
  float denom = wself;
  float acc[4];
  u16x4 hv0 = *(const u16x4*)(h + (size_t)v * 768 + b * 256 + lane * 4);
#pragma unroll
  for (int k = 0; k < 4; ++k) acc[k] = wself * b2f(hv0[k]);
  for (int j = beg; j < end; ++j) {
    int u = elist_b[j];
    float w = __expf(lrelu(s[u] + dv));
    denom += w;
    u16x4 hv = *(const u16x4*)(h + (size_t)u * 768 + b * 256 + lane * 4);
#pragma unroll
    for (int k = 0; k < 4; ++k) acc[k] += w * b2f(hv[k]);
  }
  float inv = 1.0f / denom;
  f32x4 bg4 = *(const f32x4*)(bgrow + lane * 4);
  u16x4 outv;
#pragma unroll
  for (int k = 0; k < 4; ++k) outv[k] = f2b(acc[k] * inv + bg4[k]);
  *(u16x4*)(xiall + (size_t)v * 768 + b * 256 + lane * 4) = outv;
}

// ---------------------------------------------------------------------------
extern "C" void kernel_launch(void* const* d_in, const int* in_sizes, int n_in,
                              void* d_out, int out_size, void* d_ws, size_t ws_size,
                              hipStream_t stream) {
  const float* x   = (const float*)d_in[0];
  const int* ei    = (const int*)d_in[1];
  const int* ea    = (const int*)d_in[2];
  const float* Wg  = (const float*)d_in[3];
  const float* asrc= (const float*)d_in[4];
  const float* adst= (const float*)d_in[5];
  const float* bg  = (const float*)d_in[6];
  const float* Wsm = (const float*)d_in[7];
  const float* bs  = (const float*)d_in[8];
  const float* gs  = (const float*)d_in[9];
  const float* betas=(const float*)d_in[10];
  const float* W1  = (const float*)d_in[11];
  const float* b1  = (const float*)d_in[12];
  const float* W2  = (const float*)d_in[13];
  const float* b2  = (const float*)d_in[14];
  const float* Wf  = (const float*)d_in[15];
  const float* bfv = (const float*)d_in[16];
  const float* gf  = (const float*)d_in[17];
  const float* betaf=(const float*)d_in[18];
  float* out = (float*)d_out;

  char* wsb = (char*)d_ws;
  size_t off = 0;
  auto alloc = [&](size_t bytes) -> void* {
    void* p = wsb + off;
    off += bytes;
    off = (off + 255) & ~(size_t)255;
    return p;
  };
  int* flag    = (int*)alloc(sizeof(int));
  float* g_sum = (float*)alloc(256 * sizeof(float));
  float* sw    = (float*)alloc(4 * sizeof(float));
  int* counts  = (int*)alloc((size_t)3 * NN * sizeof(int));
  int* offs    = (int*)alloc((size_t)3 * (NN + 1) * sizeof(int));
  int* cur     = (int*)alloc((size_t)3 * NN * sizeof(int));
  int* bsum    = (int*)alloc((size_t)3 * NCHUNK * sizeof(int));
  int* bpre    = (int*)alloc((size_t)3 * NCHUNK * sizeof(int));
  int* srcE    = (int*)alloc((size_t)NE * sizeof(int));
  int* dstE    = (int*)alloc((size_t)NE * sizeof(int));
  int* attrE   = (int*)alloc((size_t)NE * sizeof(int));
  int* elist   = (int*)alloc((size_t)3 * NE * sizeof(int));
  float* s_arr = (float*)alloc((size_t)3 * NN * sizeof(float));
  float* d_arr = (float*)alloc((size_t)3 * NN * sizeof(float));
  float* pSd   = (float*)alloc((size_t)6 * NN * sizeof(float));
  float* pDd   = (float*)alloc((size_t)6 * NN * sizeof(float));
  float* pS    = (float*)alloc((size_t)8 * NN * sizeof(float));
  float* pQ    = (float*)alloc((size_t)8 * NN * sizeof(float));
  float* pFS   = (float*)alloc((size_t)2 * NN * sizeof(float));
  float* pFQ   = (float*)alloc((size_t)2 * NN * sizeof(float));
  float* pg    = (float*)alloc((size_t)NPB * 256 * sizeof(float));
  u16* WT      = (u16*)alloc((size_t)8 * 65536 * sizeof(u16));
  u16* xb      = (u16*)alloc((size_t)NN * HH * sizeof(u16));
  u16* h768    = (u16*)alloc((size_t)NN * 768 * sizeof(u16));  // reused as y_raw 0..2
  u16* yb3     = (u16*)alloc((size_t)NN * 256 * sizeof(u16));  // y_raw slice 3
  u16* xiall   = (u16*)alloc((size_t)NN * 768 * sizeof(u16));
  u16* y_raw   = h768;          // 4 slices consecutive (slice 3 = yb3)
  u16* comb    = xiall;                         // overlay: xiall dead after wsgemm_s
  u16* z_raw   = xiall + (size_t)NN * 256;      // overlay: disjoint from comb
  (void)yb3; (void)ws_size; (void)in_sizes; (void)n_in; (void)out_size;

  hipMemsetAsync(flag, 0, sizeof(int), stream);
  hipMemsetAsync(g_sum, 0, 256 * sizeof(float), stream);
  hipMemsetAsync(counts, 0, (size_t)3 * NN * sizeof(int), stream);

  detect_kernel<<<1, 256, 0, stream>>>(ei, flag);
  norm_edges<<<(NE + 255) / 256, 256, 0, stream>>>(ei, ea, flag, srcE, dstE, attrE);

  transpose_all<<<dim3(8, 8, 8), dim3(32, 8), 0, stream>>>(Wg, Wsm, Wf, WT);
  xprep2<<<NPB, 256, 0, stream>>>(x, xb, pg);
  gsum_red<<<128, 256, 0, stream>>>(pg, g_sum);
  selector_kernel<<<1, 128, 0, stream>>>(g_sum, W1, b1, W2, b2, sw);

  hist_kernel<<<(NE + 255) / 256, 256, 0, stream>>>(dstE, attrE, counts);
  scan1<<<dim3(NCHUNK, 3), 256, 0, stream>>>(counts, offs, bsum);
  scan2<<<1, 64, 0, stream>>>(bsum, bpre, offs);
  scan3<<<dim3(NCHUNK, 3), 256, 0, stream>>>(bpre, offs, cur);
  scatter_kernel<<<(NE + 255) / 256, 256, 0, stream>>>(srcE, dstE, attrE, cur, elist);

  hgemm_s<<<6 * NRC, 512, 0, stream>>>(xb, WT, asrc, adst, h768, pSd, pDd, NN);
  sdfix<<<(3 * NN + 255) / 256, 256, 0, stream>>>(pSd, pDd, s_arr, d_arr);
  gat3<<<dim3(12500, 3), 256, 0, stream>>>(offs, elist, s_arr, d_arr, h768, bg, xiall);
  wsgemm_s<<<8 * NRC, 512, 0, stream>>>(xiall, xb, WT, bs, y_raw, pS, pQ, NN);
  ln4<<<12500, 256, 0, stream>>>(y_raw, pS, pQ, gs, betas, sw, comb);
  fingemm_s<<<2 * NRC, 512, 0, stream>>>(comb, WT + (size_t)7 * 65536, bfv, z_raw, pFS, pFQ, NN);
  lnout<<<12500, 256, 0, stream>>>(z_raw, pFS, pFQ, gf, betaf, out);
}

// Round 17
// 340.959 us; speedup vs baseline: 1.0851x; 1.0851x over previous
//
#include <hip/hip_runtime.h>

typedef unsigned short u16;
typedef short s16x8 __attribute__((ext_vector_type(8)));
typedef float f32x4 __attribute__((ext_vector_type(4)));
typedef u16 u16x4 __attribute__((ext_vector_type(4)));

#define NN 50000
#define NE 300000
#define HH 256
#define NCHUNK 196
#define NRC 98           // ceil(50000/512) row-chunks of 512 (4 tiles x 128)
#define NPB 12500        // xprep2 blocks (50000/4)

__device__ __forceinline__ float b2f(u16 u) {
  union { float f; unsigned int i; } v; v.i = ((unsigned int)u) << 16; return v.f;
}
__device__ __forceinline__ u16 f2b(float f) {
  union { float f; unsigned int i; } v; v.f = f;
  unsigned int u = v.i;
  unsigned int r = (u + 0x7fffu + ((u >> 16) & 1u)) >> 16;
  return (u16)r;
}
__device__ __forceinline__ float lrelu(float x) { return x > 0.f ? x : 0.2f * x; }

// Bijective XCD-chunked relabel (m204): HW assigns blockIdx round-robin to
// 8 XCDs; this gives each XCD a CONTIGUOUS logical-id range, so logical
// neighbors (which share A-panel rows) hit the same per-XCD L2. [T1]
__device__ __forceinline__ int xcd_logical(int nwg) {
  int orig = blockIdx.x;
  int xcd = orig & 7, sl = orig >> 3;
  int q = nwg >> 3, r = nwg & 7;
  return (xcd < r) ? (xcd * (q + 1) + sl) : (r * (q + 1) + (xcd - r) * q + sl);
}

#define GLOAD_LDS16(SRC, DST)                                                   \
  __builtin_amdgcn_global_load_lds(                                             \
      (const __attribute__((address_space(1))) void*)(SRC),                     \
      (__attribute__((address_space(3))) void*)(DST), 16, 0, 0)

__device__ __forceinline__ f32x4 MFMA(s16x8 a, s16x8 b, f32x4 c) {
  return __builtin_amdgcn_mfma_f32_16x16x32_bf16(a, b, c, 0, 0, 0);
}

// ---------------------------------------------------------------------------
// Stage one 128-col half of B^T (64KB) into LDS (layout: q*16384 + nf*2048 +
// ks*1024 + cq*256 + colL*16; source-permuted, linear dest — r13-verified).
// COL MAP (r15): fragment slot (nf,colL) computes logical col = half*128 +
// colL*8 + nf.
__device__ __forceinline__ void stageBhalf(const u16* __restrict__ BT, int half,
                                           char* lds, int lane, int wid) {
#pragma unroll
  for (int j = 0; j < 16; ++j) {
    int idx = j * 4 + wid;               // 0..63 x 1KB chunks
    int q = idx >> 4, rem = idx & 15;
    int nf = rem >> 1, ks = rem & 1;
    int col = half * 128 + (lane & 15) * 8 + nf;   // r15 col map
    GLOAD_LDS16((const char*)BT + col * 512 + q * 128 + ks * 64 + (lane >> 4) * 16,
                lds + idx * 1024);
  }
}

// Per row-tile compute: 32 rows/wave x 128 cols, K=256, B LDS-resident.
#define SGEMM_TILE(APTR, ASTRIDE, ACOLOFF)                                      \
  f32x4 acc[2][8] = {};                                                         \
  {                                                                             \
    s16x8 a[2][8];                                                              \
    const u16* a0p = (APTR) + (size_t)ar0 * (ASTRIDE) + (ACOLOFF) + cq8;        \
    const u16* a1p = (APTR) + (size_t)ar1 * (ASTRIDE) + (ACOLOFF) + cq8;        \
    _Pragma("unroll")                                                           \
    for (int ksp = 0; ksp < 8; ++ksp) {                                         \
      a[0][ksp] = *(const s16x8*)(a0p + ksp * 32);                              \
      a[1][ksp] = *(const s16x8*)(a1p + ksp * 32);                              \
    }                                                                           \
    _Pragma("unroll")                                                           \
    for (int ksp = 0; ksp < 8; ++ksp) {                                         \
      const char* bb = lds + (ksp >> 1) * 16384 + (ksp & 1) * 1024 + lane * 16; \
      _Pragma("unroll")                                                         \
      for (int nf = 0; nf < 8; ++nf) {                                          \
        s16x8 bf = *(const s16x8*)(bb + nf * 2048);                             \
        acc[0][nf] = MFMA(a[0][ksp], bf, acc[0][nf]);                           \
        acc[1][nf] = MFMA(a[1][ksp], bf, acc[1][nf]);                           \
      }                                                                         \
    }                                                                           \
  }

// ---------------------------------------------------------------------------
// hgemm_s: h = xb @ Wg[b] (no bias). Writes h768 raw + partial s/d dots.
__global__ __launch_bounds__(256) void hgemm_s(
    const u16* __restrict__ xb, const u16* __restrict__ WT,
    const float* __restrict__ asrc, const float* __restrict__ adst,
    u16* __restrict__ h768, float* __restrict__ pSd, float* __restrict__ pDd,
    int M) {
  __shared__ __align__(16) char lds[65536];
  int cid = xcd_logical(6 * NRC);            // [T1] same-chunk units -> same XCD
  int rem = cid % 6, chunk = cid / 6;
  int b = rem >> 1, half = rem & 1;
  int tid = threadIdx.x, lane = tid & 63, wid = tid >> 6;
  int colL = lane & 15, cq = lane >> 4, cq8 = cq * 8;

  stageBhalf(WT + (size_t)b * 65536, half, lds, lane, wid);

  float a4[8], dd4[8];
#pragma unroll
  for (int nf = 0; nf < 8; ++nf) {
    int c = half * 128 + colL * 8 + nf;          // r15 col map
    a4[nf] = asrc[b * 256 + c];
    dd4[nf] = adst[b * 256 + c];
  }
  float* st1 = pSd + (size_t)(b * 2 + half) * NN;
  float* st2 = pDd + (size_t)(b * 2 + half) * NN;
  __syncthreads();

  for (int rt = 0; rt < 4; ++rt) {
    int rowbase = chunk * 512 + rt * 128 + wid * 32;
    if (rowbase >= M) break;
    int ar0 = rowbase + colL; if (ar0 > M - 1) ar0 = M - 1;
    int ar1 = ar0 + 16; if (ar1 > M - 1) ar1 = M - 1;
    SGEMM_TILE(xb, 256, 0)
#pragma unroll
    for (int i = 0; i < 2; ++i)
#pragma unroll
      for (int r = 0; r < 4; ++r) {
        float sp = 0.f, dp = 0.f;
#pragma unroll
        for (int nf = 0; nf < 8; ++nf) {
          float v = acc[i][nf][r];
          sp += v * a4[nf]; dp += v * dd4[nf];
        }
#pragma unroll
        for (int m = 1; m < 16; m <<= 1) { sp += __shfl_xor(sp, m); dp += __shfl_xor(dp, m); }
        int row = rowbase + i * 16 + cq * 4 + r;
        if (row < M) {
          if (colL == 0) { st1[row] = sp; st2[row] = dp; }
          s16x8 o;
#pragma unroll
          for (int nf = 0; nf < 8; ++nf) o[nf] = (short)f2b(acc[i][nf][r]);
          *(s16x8*)(h768 + (size_t)row * 768 + b * 256 + half * 128 + colL * 8) = o;
        }
      }
  }
}

// ---------------------------------------------------------------------------
// wsgemm_s: y_raw[b] = A_b @ Ws[b] + bias (raw, pre-LN). Partial sum/sumsq.
__global__ __launch_bounds__(256) void wsgemm_s(
    const u16* __restrict__ xiall, const u16* __restrict__ xb,
    const u16* __restrict__ WT, const float* __restrict__ bs,
    u16* __restrict__ y_raw, float* __restrict__ pS, float* __restrict__ pQ,
    int M) {
  __shared__ __align__(16) char lds[65536];
  int cid = xcd_logical(8 * NRC);            // [T1]
  int rem = cid & 7, chunk = cid >> 3;
  int b = rem >> 1, half = rem & 1;
  int tid = threadIdx.x, lane = tid & 63, wid = tid >> 6;
  int colL = lane & 15, cq = lane >> 4, cq8 = cq * 8;

  const u16* Ap = (b < 3) ? xiall : xb;
  int strideA = (b < 3) ? 768 : 256;
  int coloffA = (b < 3) ? b * 256 : 0;

  stageBhalf(WT + (size_t)(3 + b) * 65536, half, lds, lane, wid);

  float bv[8];
#pragma unroll
  for (int nf = 0; nf < 8; ++nf)
    bv[nf] = bs[b * 256 + half * 128 + colL * 8 + nf];   // r15 col map
  float* st1 = pS + (size_t)(b * 2 + half) * NN;
  float* st2 = pQ + (size_t)(b * 2 + half) * NN;
  u16* yb = y_raw + (size_t)b * NN * 256;
  __syncthreads();

  for (int rt = 0; rt < 4; ++rt) {
    int rowbase = chunk * 512 + rt * 128 + wid * 32;
    if (rowbase >= M) break;
    int ar0 = rowbase + colL; if (ar0 > M - 1) ar0 = M - 1;
    int ar1 = ar0 + 16; if (ar1 > M - 1) ar1 = M - 1;
    SGEMM_TILE(Ap, strideA, coloffA)
#pragma unroll
    for (int i = 0; i < 2; ++i)
#pragma unroll
      for (int r = 0; r < 4; ++r) {
        float s = 0.f, q = 0.f;
#pragma unroll
        for (int nf = 0; nf < 8; ++nf) {
          float v = acc[i][nf][r] + bv[nf];
          acc[i][nf][r] = v;
          s += v; q += v * v;
        }
#pragma unroll
        for (int m = 1; m < 16; m <<= 1) { s += __shfl_xor(s, m); q += __shfl_xor(q, m); }
        int row = rowbase + i * 16 + cq * 4 + r;
        if (row < M) {
          if (colL == 0) { st1[row] = s; st2[row] = q; }
          s16x8 o;
#pragma unroll
          for (int nf = 0; nf < 8; ++nf) o[nf] = (short)f2b(acc[i][nf][r]);
          *(s16x8*)(yb + (size_t)row * 256 + half * 128 + colL * 8) = o;
        }
      }
  }
}

// ---------------------------------------------------------------------------
// fingemm_s: z_raw = comb @ Wf + bf (raw). Partial sum/sumsq.
__global__ __launch_bounds__(256) void fingemm_s(
    const u16* __restrict__ comb, const u16* __restrict__ WT7,
    const float* __restrict__ bfv, u16* __restrict__ z_raw,
    float* __restrict__ pFS, float* __restrict__ pFQ, int M) {
  __shared__ __align__(16) char lds[65536];
  int cid = xcd_logical(2 * NRC);            // [T1]
  int half = cid & 1, chunk = cid >> 1;
  int tid = threadIdx.x, lane = tid & 63, wid = tid >> 6;
  int colL = lane & 15, cq = lane >> 4, cq8 = cq * 8;

  stageBhalf(WT7, half, lds, lane, wid);

  float bv[8];
#pragma unroll
  for (int nf = 0; nf < 8; ++nf)
    bv[nf] = bfv[half * 128 + colL * 8 + nf];            // r15 col map
  float* st1 = pFS + (size_t)half * NN;
  float* st2 = pFQ + (size_t)half * NN;
  __syncthreads();

  for (int rt = 0; rt < 4; ++rt) {
    int rowbase = chunk * 512 + rt * 128 + wid * 32;
    if (rowbase >= M) break;
    int ar0 = rowbase + colL; if (ar0 > M - 1) ar0 = M - 1;
    int ar1 = ar0 + 16; if (ar1 > M - 1) ar1 = M - 1;
    SGEMM_TILE(comb, 256, 0)
#pragma unroll
    for (int i = 0; i < 2; ++i)
#pragma unroll
      for (int r = 0; r < 4; ++r) {
        float s = 0.f, q = 0.f;
#pragma unroll
        for (int nf = 0; nf < 8; ++nf) {
          float v = acc[i][nf][r] + bv[nf];
          acc[i][nf][r] = v;
          s += v; q += v * v;
        }
#pragma unroll
        for (int m = 1; m < 16; m <<= 1) { s += __shfl_xor(s, m); q += __shfl_xor(q, m); }
        int row = rowbase + i * 16 + cq * 4 + r;
        if (row < M) {
          if (colL == 0) { st1[row] = s; st2[row] = q; }
          s16x8 o;
#pragma unroll
          for (int nf = 0; nf < 8; ++nf) o[nf] = (short)f2b(acc[i][nf][r]);
          *(s16x8*)(z_raw + (size_t)row * 256 + half * 128 + colL * 8) = o;
        }
      }
  }
}

// ---------------------------------------------------------------------------
// sdfix: s_arr[b*NN+v] = pSd[2b][v] + pSd[2b+1][v]; same for d.
__global__ void sdfix(const float* __restrict__ pSd, const float* __restrict__ pDd,
                      float* __restrict__ s_arr, float* __restrict__ d_arr) {
  int i = blockIdx.x * 256 + threadIdx.x;
  if (i >= 3 * NN) return;
  int b = i / NN, v = i - b * NN;
  s_arr[i] = pSd[(size_t)(2 * b) * NN + v] + pSd[(size_t)(2 * b + 1) * NN + v];
  d_arr[i] = pDd[(size_t)(2 * b) * NN + v] + pDd[(size_t)(2 * b + 1) * NN + v];
}

// ln4: comb[v] = sum_b sw[b] * relu(LN_b(y_raw[b][v])); one wave per row.
__global__ void ln4(const u16* __restrict__ y_raw, const float* __restrict__ pS,
                    const float* __restrict__ pQ, const float* __restrict__ gs,
                    const float* __restrict__ betas, const float* __restrict__ sw,
                    u16* __restrict__ comb) {
  int v = blockIdx.x * 4 + (threadIdx.x >> 6);
  int lane = threadIdx.x & 63;
  int c0 = lane * 4;
  float accv[4] = {0.f, 0.f, 0.f, 0.f};
#pragma unroll
  for (int b = 0; b < 4; ++b) {
    float s = pS[(size_t)(2 * b) * NN + v] + pS[(size_t)(2 * b + 1) * NN + v];
    float q = pQ[(size_t)(2 * b) * NN + v] + pQ[(size_t)(2 * b + 1) * NN + v];
    float mu = s * (1.0f / HH);
    float var = q * (1.0f / HH) - mu * mu;
    float rs = rsqrtf(var + 1e-5f);
    float w = sw[b];
    u16x4 yv = *(const u16x4*)(y_raw + ((size_t)b * NN + v) * 256 + c0);
#pragma unroll
    for (int k = 0; k < 4; ++k) {
      float t = (b2f(yv[k]) - mu) * rs * gs[b * 256 + c0 + k] + betas[b * 256 + c0 + k];
      accv[k] += w * (t > 0.f ? t : 0.f);
    }
  }
  u16x4 o;
#pragma unroll
  for (int k = 0; k < 4; ++k) o[k] = f2b(accv[k]);
  *(u16x4*)(comb + (size_t)v * 256 + c0) = o;
}

// lnout: out[v] = relu(LN(z_raw[v])) as f32; one wave per row.
__global__ void lnout(const u16* __restrict__ z_raw, const float* __restrict__ pFS,
                      const float* __restrict__ pFQ, const float* __restrict__ gf,
                      const float* __restrict__ betaf, float* __restrict__ outf) {
  int v = blockIdx.x * 4 + (threadIdx.x >> 6);
  int lane = threadIdx.x & 63;
  int c0 = lane * 4;
  float s = pFS[v] + pFS[(size_t)NN + v];
  float q = pFQ[v] + pFQ[(size_t)NN + v];
  float mu = s * (1.0f / HH);
  float var = q * (1.0f / HH) - mu * mu;
  float rs = rsqrtf(var + 1e-5f);
  u16x4 zv = *(const u16x4*)(z_raw + (size_t)v * 256 + c0);
  f32x4 o;
#pragma unroll
  for (int k = 0; k < 4; ++k) {
    float t = (b2f(zv[k]) - mu) * rs * gf[c0 + k] + betaf[c0 + k];
    o[k] = t > 0.f ? t : 0.f;
  }
  *(f32x4*)(outf + (size_t)v * 256 + c0) = o;
}

// ---------------------------------------------------------------------------
// xprep2: one row per wave, no loop; per-block column partials (no atomics).
__global__ void xprep2(const float* __restrict__ x, u16* __restrict__ xb,
                       float* __restrict__ pg) {
  int tid = threadIdx.x, lane = tid & 63, w = tid >> 6;
  int r = blockIdx.x * 4 + w;
  f32x4 v = *(const f32x4*)(x + (size_t)r * HH + lane * 4);
  u16x4 o;
#pragma unroll
  for (int k = 0; k < 4; ++k) o[k] = f2b(v[k]);
  *(u16x4*)(xb + (size_t)r * HH + lane * 4) = o;
  __shared__ f32x4 sh[256];
  sh[tid] = v;
  __syncthreads();
  if (tid < 64) {
    f32x4 t = sh[tid] + sh[tid + 64] + sh[tid + 128] + sh[tid + 192];
    *(f32x4*)(pg + (size_t)blockIdx.x * 256 + lane * 4) = t;
  }
}

__global__ void gsum_red(const float* __restrict__ pg, float* __restrict__ g_sum) {
  int t = threadIdx.x;
  int r0 = blockIdx.x * 98;
  float s = 0.f;
  for (int r = r0; r < r0 + 98 && r < NPB; ++r) s += pg[(size_t)r * 256 + t];
  atomicAdd(&g_sum[t], s);
}

// 8 weight transposes: WT[z][n][k] = bf16(src_z[k][n])
__global__ void transpose_all(const float* __restrict__ Wg, const float* __restrict__ Wsm,
                              const float* __restrict__ Wf, u16* __restrict__ WT) {
  __shared__ float tile[32][33];
  int z = blockIdx.z;
  const float* src = (z < 3) ? (Wg + (size_t)z * 65536)
                   : (z < 7) ? (Wsm + (size_t)(z - 3) * 65536) : Wf;
  u16* dst = WT + (size_t)z * 65536;
  int tx = threadIdx.x, ty = threadIdx.y;
  int bx = blockIdx.x, by = blockIdx.y;
#pragma unroll
  for (int j = 0; j < 32; j += 8)
    tile[ty + j][tx] = src[(size_t)(by * 32 + ty + j) * 256 + bx * 32 + tx];
  __syncthreads();
#pragma unroll
  for (int j = 0; j < 32; j += 8)
    dst[(size_t)(bx * 32 + ty + j) * 256 + by * 32 + tx] = f2b(tile[tx][ty + j]);
}

__global__ void selector_kernel(const float* __restrict__ g_sum,
                                const float* __restrict__ W1, const float* __restrict__ b1,
                                const float* __restrict__ W2, const float* __restrict__ b2,
                                float* __restrict__ sw) {
  __shared__ float gg[256];
  __shared__ float hid[128];
  __shared__ float lg[4];
  int t = threadIdx.x;  // 128
  gg[t] = g_sum[t] * (1.0f / NN);
  gg[t + 128] = g_sum[t + 128] * (1.0f / NN);
  __syncthreads();
  float a = 0.f;
  for (int c = 0; c < 256; ++c) a += gg[c] * W1[c * 128 + t];
  a += b1[t];
  hid[t] = a > 0.f ? a : 0.f;
  __syncthreads();
  if (t < 4) {
    float s = 0.f;
    for (int j = 0; j < 128; ++j) s += hid[j] * W2[j * 4 + t];
    lg[t] = s + b2[t];
  }
  __syncthreads();
  if (t == 0) {
    float m = fmaxf(fmaxf(lg[0], lg[1]), fmaxf(lg[2], lg[3]));
    float e0 = __expf(lg[0] - m), e1 = __expf(lg[1] - m);
    float e2 = __expf(lg[2] - m), e3 = __expf(lg[3] - m);
    float inv = 1.0f / (e0 + e1 + e2 + e3);
    sw[0] = e0 * inv; sw[1] = e1 * inv; sw[2] = e2 * inv; sw[3] = e3 * inv;
  }
}

// ---------------------------------------------------------------------------
__global__ void detect_kernel(const int* __restrict__ ei_raw, int* __restrict__ flag) {
  int t = threadIdx.x;
  int nz = 0;
  for (int k = t; k < 1024; k += 256) nz |= (ei_raw[2 * k + 1] != 0);
  if (nz) atomicOr(flag, 1);
}

__global__ void norm_edges(const int* __restrict__ ei_raw, const int* __restrict__ ea_raw,
                           const int* __restrict__ flag, int* __restrict__ srcE,
                           int* __restrict__ dstE, int* __restrict__ attrE) {
  int e = blockIdx.x * 256 + threadIdx.x;
  if (e >= NE) return;
  if (*flag) {
    srcE[e] = ei_raw[e];
    dstE[e] = ei_raw[NE + e];
    attrE[e] = ea_raw[e];
  } else {
    srcE[e] = ei_raw[2 * e];
    dstE[e] = ei_raw[2 * NE + 2 * e];
    attrE[e] = ea_raw[2 * e];
  }
}

__global__ void hist_kernel(const int* __restrict__ dstE, const int* __restrict__ attrE,
                            int* __restrict__ counts) {
  int e = blockIdx.x * 256 + threadIdx.x;
  if (e < NE) {
    int a = attrE[e];
    if ((unsigned)a < 3u) atomicAdd(&counts[a * NN + dstE[e]], 1);
  }
}

__global__ void scan1(const int* __restrict__ counts, int* __restrict__ offs,
                      int* __restrict__ bsum) {
  int b = blockIdx.y, c = blockIdx.x, t = threadIdx.x;
  int idx = c * 256 + t;
  int v = (idx < NN) ? counts[b * NN + idx] : 0;
  __shared__ int sh[256];
  sh[t] = v;
  __syncthreads();
  for (int o = 1; o < 256; o <<= 1) {
    int add = (t >= o) ? sh[t - o] : 0;
    __syncthreads();
    sh[t] += add;
    __syncthreads();
  }
  int incl = sh[t];
  if (idx < NN) offs[b * (NN + 1) + idx] = incl - v;
  if (t == 255) bsum[b * NCHUNK + c] = incl;
}

__global__ void scan2(const int* __restrict__ bsum, int* __restrict__ bpre,
                      int* __restrict__ offs) {
  int t = threadIdx.x;
  if (t < 3) {
    int run = 0;
    for (int c = 0; c < NCHUNK; ++c) { bpre[t * NCHUNK + c] = run; run += bsum[t * NCHUNK + c]; }
    offs[t * (NN + 1) + NN] = run;
  }
}

__global__ void scan3(const int* __restrict__ bpre, int* __restrict__ offs,
                      int* __restrict__ cur) {
  int b = blockIdx.y, c = blockIdx.x;
  int idx = c * 256 + threadIdx.x;
  if (idx < NN) {
    int val = offs[b * (NN + 1) + idx] + bpre[b * NCHUNK + c];
    offs[b * (NN + 1) + idx] = val;
    cur[b * NN + idx] = val;
  }
}

__global__ void scatter_kernel(const int* __restrict__ srcE, const int* __restrict__ dstE,
                               const int* __restrict__ attrE, int* __restrict__ cur,
                               int* __restrict__ elist) {
  int e = blockIdx.x * 256 + threadIdx.x;
  if (e < NE) {
    int a = attrE[e];
    if ((unsigned)a < 3u) {
      int p = atomicAdd(&cur[a * NN + dstE[e]], 1);
      elist[a * NE + p] = srcE[e];
    }
  }
}

// ---------------------------------------------------------------------------
// GAT aggregation, 3 branches in one dispatch. Single-pass softmax (r15):
// logits lrelu(s+d) are O(1), exp() overflow-safe without max-subtraction.
__global__ void gat3(const int* __restrict__ offs, const int* __restrict__ elist,
                     const float* __restrict__ s_all, const float* __restrict__ d_all,
                     const u16* __restrict__ h, const float* __restrict__ bg,
                     u16* __restrict__ xiall) {
  int b = blockIdx.y;
  const int* offs_b = offs + (size_t)b * (NN + 1);
  const int* elist_b = elist + (size_t)b * NE;
  const float* s = s_all + (size_t)b * NN;
  const float* d = d_all + (size_t)b * NN;
  const float* bgrow = bg + b * 256;
  int v = blockIdx.x * 4 + (threadIdx.x >> 6);
  int lane = threadIdx.x & 63;
  float dv = d[v], sv = s[v];
  int beg = offs_b[v], end = offs_b[v + 1];
  float wself = __expf(lrelu(sv + dv));
  float denom = wself;
  float acc[4];
  u16x4 hv0 = *(const u16x4*)(h + (size_t)v * 768 + b * 256 + lane * 4);
#pragma unroll
  for (int k = 0; k < 4; ++k) acc[k] = wself * b2f(hv0[k]);
  for (int j = beg; j < end; ++j) {
    int u = elist_b[j];
    float w = __expf(lrelu(s[u] + dv));
    denom += w;
    u16x4 hv = *(const u16x4*)(h + (size_t)u * 768 + b * 256 + lane * 4);
#pragma unroll
    for (int k = 0; k < 4; ++k) acc[k] += w * b2f(hv[k]);
  }
  float inv = 1.0f / denom;
  f32x4 bg4 = *(const f32x4*)(bgrow + lane * 4);
  u16x4 outv;
#pragma unroll
  for (int k = 0; k < 4; ++k) outv[k] = f2b(acc[k] * inv + bg4[k]);
  *(u16x4*)(xiall + (size_t)v * 768 + b * 256 + lane * 4) = outv;
}

// ---------------------------------------------------------------------------
extern "C" void kernel_launch(void* const* d_in, const int* in_sizes, int n_in,
                              void* d_out, int out_size, void* d_ws, size_t ws_size,
                              hipStream_t stream) {
  const float* x   = (const float*)d_in[0];
  const int* ei    = (const int*)d_in[1];
  const int* ea    = (const int*)d_in[2];
  const float* Wg  = (const float*)d_in[3];
  const float* asrc= (const float*)d_in[4];
  const float* adst= (const float*)d_in[5];
  const float* bg  = (const float*)d_in[6];
  const float* Wsm = (const float*)d_in[7];
  const float* bs  = (const float*)d_in[8];
  const float* gs  = (const float*)d_in[9];
  const float* betas=(const float*)d_in[10];
  const float* W1  = (const float*)d_in[11];
  const float* b1  = (const float*)d_in[12];
  const float* W2  = (const float*)d_in[13];
  const float* b2  = (const float*)d_in[14];
  const float* Wf  = (const float*)d_in[15];
  const float* bfv = (const float*)d_in[16];
  const float* gf  = (const float*)d_in[17];
  const float* betaf=(const float*)d_in[18];
  float* out = (float*)d_out;

  char* wsb = (char*)d_ws;
  size_t off = 0;
  auto alloc = [&](size_t bytes) -> void* {
    void* p = wsb + off;
    off += bytes;
    off = (off + 255) & ~(size_t)255;
    return p;
  };
  int* flag    = (int*)alloc(sizeof(int));
  float* g_sum = (float*)alloc(256 * sizeof(float));
  float* sw    = (float*)alloc(4 * sizeof(float));
  int* counts  = (int*)alloc((size_t)3 * NN * sizeof(int));
  int* offs    = (int*)alloc((size_t)3 * (NN + 1) * sizeof(int));
  int* cur     = (int*)alloc((size_t)3 * NN * sizeof(int));
  int* bsum    = (int*)alloc((size_t)3 * NCHUNK * sizeof(int));
  int* bpre    = (int*)alloc((size_t)3 * NCHUNK * sizeof(int));
  int* srcE    = (int*)alloc((size_t)NE * sizeof(int));
  int* dstE    = (int*)alloc((size_t)NE * sizeof(int));
  int* attrE   = (int*)alloc((size_t)NE * sizeof(int));
  int* elist   = (int*)alloc((size_t)3 * NE * sizeof(int));
  float* s_arr = (float*)alloc((size_t)3 * NN * sizeof(float));
  float* d_arr = (float*)alloc((size_t)3 * NN * sizeof(float));
  float* pSd   = (float*)alloc((size_t)6 * NN * sizeof(float));
  float* pDd   = (float*)alloc((size_t)6 * NN * sizeof(float));
  float* pS    = (float*)alloc((size_t)8 * NN * sizeof(float));
  float* pQ    = (float*)alloc((size_t)8 * NN * sizeof(float));
  float* pFS   = (float*)alloc((size_t)2 * NN * sizeof(float));
  float* pFQ   = (float*)alloc((size_t)2 * NN * sizeof(float));
  float* pg    = (float*)alloc((size_t)NPB * 256 * sizeof(float));
  u16* WT      = (u16*)alloc((size_t)8 * 65536 * sizeof(u16));
  u16* xb      = (u16*)alloc((size_t)NN * HH * sizeof(u16));
  u16* h768    = (u16*)alloc((size_t)NN * 768 * sizeof(u16));  // reused as y_raw 0..2
  u16* yb3     = (u16*)alloc((size_t)NN * 256 * sizeof(u16));  // y_raw slice 3
  u16* xiall   = (u16*)alloc((size_t)NN * 768 * sizeof(u16));
  u16* y_raw   = h768;          // 4 slices consecutive (slice 3 = yb3)
  u16* comb    = xiall;                         // overlay: xiall dead after wsgemm_s
  u16* z_raw   = xiall + (size_t)NN * 256;      // overlay: disjoint from comb
  (void)yb3; (void)ws_size; (void)in_sizes; (void)n_in; (void)out_size;

  hipMemsetAsync(flag, 0, sizeof(int), stream);
  hipMemsetAsync(g_sum, 0, 256 * sizeof(float), stream);
  hipMemsetAsync(counts, 0, (size_t)3 * NN * sizeof(int), stream);

  detect_kernel<<<1, 256, 0, stream>>>(ei, flag);
  norm_edges<<<(NE + 255) / 256, 256, 0, stream>>>(ei, ea, flag, srcE, dstE, attrE);

  transpose_all<<<dim3(8, 8, 8), dim3(32, 8), 0, stream>>>(Wg, Wsm, Wf, WT);
  xprep2<<<NPB, 256, 0, stream>>>(x, xb, pg);
  gsum_red<<<128, 256, 0, stream>>>(pg, g_sum);
  selector_kernel<<<1, 128, 0, stream>>>(g_sum, W1, b1, W2, b2, sw);

  hist_kernel<<<(NE + 255) / 256, 256, 0, stream>>>(dstE, attrE, counts);
  scan1<<<dim3(NCHUNK, 3), 256, 0, stream>>>(counts, offs, bsum);
  scan2<<<1, 64, 0, stream>>>(bsum, bpre, offs);
  scan3<<<dim3(NCHUNK, 3), 256, 0, stream>>>(bpre, offs, cur);
  scatter_kernel<<<(NE + 255) / 256, 256, 0, stream>>>(srcE, dstE, attrE, cur, elist);

  hgemm_s<<<6 * NRC, 256, 0, stream>>>(xb, WT, asrc, adst, h768, pSd, pDd, NN);
  sdfix<<<(3 * NN + 255) / 256, 256, 0, stream>>>(pSd, pDd, s_arr, d_arr);
  gat3<<<dim3(12500, 3), 256, 0, stream>>>(offs, elist, s_arr, d_arr, h768, bg, xiall);
  wsgemm_s<<<8 * NRC, 256, 0, stream>>>(xiall, xb, WT, bs, y_raw, pS, pQ, NN);
  ln4<<<12500, 256, 0, stream>>>(y_raw, pS, pQ, gs, betas, sw, comb);
  fingemm_s<<<2 * NRC, 256, 0, stream>>>(comb, WT + (size_t)7 * 65536, bfv, z_raw, pFS, pFQ, NN);
  lnout<<<12500, 256, 0, stream>>>(z_raw, pFS, pFQ, gf, betaf, out);
}